// Round 3
// baseline (1050.834 us; speedup 1.0000x reference)
//
#include <hip/hip_runtime.h>
#include <math.h>

#define BB 8
#define DSEM 256
#define DAC 36
#define DTOT 292
#define TT 4096
#define NCB 8192
#define NROWS (BB*TT)          // 32768

// output flat offsets (all float32)
static constexpr size_t O0 = 0;          // z_q (8,292,4096)
static constexpr size_t O1 = 9568256;    // sem_indices (8,4096)
static constexpr size_t O2 = 9601024;    // ac_codes (8,36,4096)
static constexpr size_t O3 = 10780672;   // vq_loss scalar
static constexpr size_t O4 = 10780673;   // z_ac_q (8,36,4096)

typedef __attribute__((ext_vector_type(8))) short bf16x8;
typedef __attribute__((ext_vector_type(4))) float f32x4;

__device__ __forceinline__ unsigned short f2bf(float x) {
  unsigned u = __float_as_uint(x);
  unsigned r = (u + 0x7FFFu + ((u >> 16) & 1u)) >> 16;
  return (unsigned short)r;
}

__device__ __forceinline__ void gload_lds16(const void* g, void* lds) {
  __builtin_amdgcn_global_load_lds(
      (const __attribute__((address_space(1))) void*)g,
      (__attribute__((address_space(3))) void*)lds, 16, 0, 0);
}

// ---------------- shared small kernels (both paths) ----------------

__global__ __launch_bounds__(256) void k_csq(const float* __restrict__ cb,
                                             float* __restrict__ csq,
                                             double* __restrict__ loss) {
  if (blockIdx.x == 0 && threadIdx.x == 0) loss[0] = 0.0;
  int w = (blockIdx.x << 2) + (threadIdx.x >> 6);
  int lane = threadIdx.x & 63;
  float4 v = *reinterpret_cast<const float4*>(cb + (size_t)w * DSEM + lane * 4);
  float s = v.x * v.x + v.y * v.y + v.z * v.z + v.w * v.w;
  for (int off = 32; off; off >>= 1) s += __shfl_xor(s, off);
  if (lane == 0) csq[w] = s;
}

__global__ __launch_bounds__(256) void k_rn(const float* __restrict__ z,
                                            float* __restrict__ rn) {
  int r = blockIdx.x * 256 + threadIdx.x;
  int b = r >> 12, t = r & 4095;
  const float* p = z + ((size_t)(b * DTOT) << 12) + t;
  double acc = 0.0;
  #pragma unroll 8
  for (int d = 0; d < DSEM; ++d) {
    float v = p[(size_t)d << 12];
    acc += (double)v * (double)v;
  }
  rn[r] = (float)acc;
}

__global__ __launch_bounds__(256) void k_fsq(const float* __restrict__ z,
                                             float* __restrict__ out) {
  int e = blockIdx.x * 256 + threadIdx.x;   // < 1179648
  int b = e / (DAC * TT);
  int rem = e - b * (DAC * TT);
  int d = rem >> 12, t = rem & 4095;
  float zv = z[((size_t)(b * DTOT + DSEM + d) << 12) + t];
  float th = (float)tanh((double)zv);
  float zb = th * 10.001f;
  float zq = rintf(zb);
  int code = (int)(zq + 10.0f);
  code = code < 0 ? 0 : (code > 20 ? 20 : code);
  out[O0 + (((size_t)(b * DTOT + DSEM + d)) << 12) + t] = zq;
  out[O2 + e] = (float)code;
  out[O4 + e] = zq;
}

__global__ __launch_bounds__(256) void k_loss(const float* __restrict__ z,
                                              const float* __restrict__ cb,
                                              const int* __restrict__ idx,
                                              float* __restrict__ out0,
                                              double* __restrict__ loss) {
  float s = 0.f;
  for (int e = blockIdx.x * 256 + threadIdx.x; e < BB * DSEM * TT; e += 2048 * 256) {
    int b = e >> 20;
    int rem = e & 1048575;
    int d = rem >> 12, t = rem & 4095;
    int r = (b << 12) + t;
    int j = idx[r];
    float c = cb[(size_t)j * DSEM + d];
    size_t zi = ((size_t)(b * DTOT + d) << 12) + t;
    float zv = z[zi];
    out0[zi] = c;
    float df = c - zv;
    s += df * df;
  }
  for (int off = 32; off; off >>= 1) s += __shfl_xor(s, off);
  __shared__ float ws4[4];
  int lane = threadIdx.x & 63, w = threadIdx.x >> 6;
  if (lane == 0) ws4[w] = s;
  __syncthreads();
  if (threadIdx.x == 0) {
    float tot = ws4[0] + ws4[1] + ws4[2] + ws4[3];
    atomicAdd(loss, (double)tot);
  }
}

__global__ void k_fin(const double* __restrict__ loss, float* __restrict__ out3) {
  out3[0] = (float)(1.25 * loss[0] / 8388608.0);
}

// ---------------- MFMA path ----------------

// transpose z_sem (b,k,t) -> A' bf16 [row=(b,t)][k]
__global__ __launch_bounds__(256) void k_prepA(const float* __restrict__ z,
                                               unsigned short* __restrict__ Abf) {
  __shared__ float tile[64][65];
  int bid = blockIdx.x;
  int tt = bid & 63, kt = (bid >> 6) & 3, b = bid >> 8;
  int k0 = kt * 64, t0 = tt * 64;
  int tid = threadIdx.x;
  #pragma unroll
  for (int i = 0; i < 16; ++i) {
    int flat = i * 256 + tid;
    int kk = flat >> 6, t2 = flat & 63;
    tile[kk][t2] = z[((size_t)(b * DTOT + k0 + kk) << 12) + t0 + t2];
  }
  __syncthreads();
  #pragma unroll
  for (int i = 0; i < 16; ++i) {
    int flat = i * 256 + tid;
    int t2 = flat >> 6, kk = flat & 63;
    Abf[(size_t)(b * 4096 + t0 + t2) * 256 + k0 + kk] = f2bf(tile[kk][t2]);
  }
}

// B' bf16 [j][k] = bf16(-2 * cb[j][k])
__global__ __launch_bounds__(256) void k_prepB(const float* __restrict__ cb,
                                               unsigned short* __restrict__ Bbf) {
  int e = blockIdx.x * 256 + threadIdx.x;   // < 2097152
  Bbf[e] = f2bf(-2.0f * cb[e]);
}

// coarse GEMM: acc = sum bf16(z)*bf16(-2c); per-32col-unit min of (acc+csq)
// tmin layout: [row][unit]  (32768 x 256 floats)
__global__ __launch_bounds__(256) void k_gemm(const unsigned short* __restrict__ A,
                                              const unsigned short* __restrict__ B,
                                              const float* __restrict__ csq,
                                              float* __restrict__ tmin) {
  __shared__ char smraw[128 * 68 * 4];   // 34816 B; aliases As|Bs then red
  unsigned short* As = (unsigned short*)smraw;           // [128][64]
  unsigned short* Bs = (unsigned short*)(smraw + 16384); // [128][64]
  float* red = (float*)smraw;                            // [128][68]

  int bid = blockIdx.x;
  int wg = (bid & 7) * 2048 + (bid >> 3);   // XCD swizzle (16384 % 8 == 0)
  int mtile = wg >> 6, ntile = wg & 63;
  int rbase = mtile << 7, cbase = ntile << 7;
  int tid = threadIdx.x, lane = tid & 63, wid = tid >> 6;
  int wm = wid >> 1, wn = wid & 1;
  int l15 = lane & 15, l4 = lane >> 4;

  f32x4 acc[4][4];
  #pragma unroll
  for (int mi = 0; mi < 4; ++mi)
    #pragma unroll
    for (int ni = 0; ni < 4; ++ni) acc[mi][ni] = (f32x4){0.f, 0.f, 0.f, 0.f};

  for (int kt = 0; kt < 4; ++kt) {
    int kb = kt << 6;
    __syncthreads();
    #pragma unroll
    for (int i = 0; i < 4; ++i) {
      int flat = (wid * 4 + i) * 64 + lane;   // 0..1023
      int row = flat >> 3, kk = (flat & 7) << 3;
      gload_lds16(A + (size_t)(rbase + row) * 256 + kb + kk, (char*)As + flat * 16);
      gload_lds16(B + (size_t)(cbase + row) * 256 + kb + kk, (char*)Bs + flat * 16);
    }
    __syncthreads();
    #pragma unroll
    for (int ks = 0; ks < 2; ++ks) {
      int ko = (ks << 5) + (l4 << 3);
      bf16x8 af[4], bv[4];
      #pragma unroll
      for (int mi = 0; mi < 4; ++mi)
        af[mi] = *(const bf16x8*)(As + ((wm * 64 + mi * 16 + l15) << 6) + ko);
      #pragma unroll
      for (int ni = 0; ni < 4; ++ni)
        bv[ni] = *(const bf16x8*)(Bs + ((wn * 64 + ni * 16 + l15) << 6) + ko);
      #pragma unroll
      for (int mi = 0; mi < 4; ++mi)
        #pragma unroll
        for (int ni = 0; ni < 4; ++ni)
          acc[mi][ni] = __builtin_amdgcn_mfma_f32_16x16x32_bf16(af[mi], bv[ni], acc[mi][ni], 0, 0, 0);
    }
  }

  // epilogue: d = acc + csq[col]; per-row min over 32-col units
  float csv[4];
  #pragma unroll
  for (int ni = 0; ni < 4; ++ni) csv[ni] = csq[cbase + wn * 64 + ni * 16 + l15];

  __syncthreads();   // everyone done reading As/Bs before aliasing as red
  #pragma unroll
  for (int mi = 0; mi < 4; ++mi) {
    #pragma unroll
    for (int r = 0; r < 4; ++r) {
      int row = wm * 64 + mi * 16 + l4 * 4 + r;
      float v0 = fminf(acc[mi][0][r] + csv[0], acc[mi][1][r] + csv[1]);
      float v1 = fminf(acc[mi][2][r] + csv[2], acc[mi][3][r] + csv[3]);
      red[row * 68 + (wn * 2 + 0) * 16 + l15] = v0;
      red[row * 68 + (wn * 2 + 1) * 16 + l15] = v1;
    }
  }
  __syncthreads();
  if (tid < 128) {
    int row = tid;
    const float* rp = red + row * 68;
    float4 o4;
    #pragma unroll
    for (int q = 0; q < 4; ++q) {
      float m = rp[q * 16];
      #pragma unroll
      for (int x = 1; x < 16; ++x) m = fminf(m, rp[q * 16 + x]);
      ((float*)&o4)[q] = m;
    }
    *reinterpret_cast<float4*>(tmin + (size_t)(rbase + row) * 256 + ntile * 4) = o4;
  }
}

// exact rescan: block = 64 consecutive rows (same b, consecutive t).
// z staged coalesced into LDS; tmin read coalesced [row][unit];
// ballot+ctz walk of candidate units; exact fp32 fmaf metric.
__global__ __launch_bounds__(256) void k_rescan(const float* __restrict__ z,
                                                const float* __restrict__ cb,
                                                const float* __restrict__ csq,
                                                const float* __restrict__ rn,
                                                const float* __restrict__ tmin,
                                                int* __restrict__ widx,
                                                float* __restrict__ out1) {
  __shared__ float zs[256][64];   // 64 KB: zs[k][t2]
  int tid = threadIdx.x;
  int row0 = blockIdx.x << 6;
  int b = row0 >> 12, t0 = row0 & 4095;
  int tloc = tid & 63, kq = tid >> 6;
  // stage: wave w loads k = i*4+w, contiguous 64 floats in t
  for (int i = 0; i < 64; ++i) {
    int k = i * 4 + kq;
    zs[k][tloc] = z[((size_t)(b * DTOT + k) << 12) + t0 + tloc];
  }
  __syncthreads();

  int wv = tid >> 6, lane = tid & 63;
  for (int rr = wv; rr < 64; rr += 4) {
    int row = row0 + rr;
    const float* tp = tmin + (size_t)row * 256;
    float v[4];
    #pragma unroll
    for (int i = 0; i < 4; ++i) v[i] = tp[i * 64 + lane];
    float g = fminf(fminf(v[0], v[1]), fminf(v[2], v[3]));
    #pragma unroll
    for (int off = 32; off; off >>= 1) g = fminf(g, __shfl_xor(g, off));
    float thr = g + 6e-4f;
    float an = rn[row];

    unsigned long long best = 0xFFFFFFFFFFFFFFFFULL;
    #pragma unroll
    for (int i = 0; i < 4; ++i) {
      unsigned long long mask = __ballot(v[i] <= thr);
      while (mask) {
        int sl = __builtin_ctzll(mask);
        mask &= mask - 1;
        int s = i * 64 + sl;
        int j = s * 32 + (lane & 31);
        const float* cp = cb + (size_t)j * 256;
        float m = 0.f;
        #pragma unroll 8
        for (int k = 0; k < 256; ++k) m = fmaf(zs[k][rr], cp[k], m);
        float d = (an - 2.f * m) + csq[j];
        unsigned long long pk =
            (((unsigned long long)__float_as_uint(d)) << 32) | (unsigned int)j;
        #pragma unroll
        for (int off = 32; off; off >>= 1) {
          unsigned long long o = __shfl_xor(pk, off);
          if (o < pk) pk = o;
        }
        if (pk < best) best = pk;
      }
    }
    if (lane == 0) {
      int j = (int)(best & 0xFFFFFFFFULL);
      widx[row] = j;
      out1[row] = (float)j;
    }
  }
}

// ---------------- round-1 fallback path (fp32 vector GEMM) ----------------

__global__ __launch_bounds__(256) void k_vq(const float* __restrict__ z,
                                            const float* __restrict__ cb,
                                            const float* __restrict__ csq,
                                            const float* __restrict__ rn,
                                            float* __restrict__ pmin,
                                            int* __restrict__ pidx) {
  __shared__ float As[32][132];
  __shared__ float Bs[32][132];
  const int tid = threadIdx.x;
  const int tx = tid & 15, ty = tid >> 4;
  const int mb = blockIdx.x >> 2, s = blockIdx.x & 3;
  const int r0 = mb << 7;
  const int b = r0 >> 12, t0 = r0 & 4095;
  const int nbase = s * 2048;

  int mrow[8], jcol[8];
  #pragma unroll
  for (int i = 0; i < 4; ++i) {
    mrow[i] = ty * 4 + i;  mrow[i + 4] = 64 + ty * 4 + i;
    jcol[i] = tx * 4 + i;  jcol[i + 4] = 64 + tx * 4 + i;
  }
  float an[8];
  #pragma unroll
  for (int i = 0; i < 8; ++i) an[i] = rn[r0 + mrow[i]];

  float rmin[8]; int ridx[8];
  #pragma unroll
  for (int i = 0; i < 8; ++i) { rmin[i] = 3.402823466e38f; ridx[i] = 0; }

  for (int nc = 0; nc < 16; ++nc) {
    const int n0 = nbase + nc * 128;
    float acc[8][8];
    #pragma unroll
    for (int i = 0; i < 8; ++i)
      #pragma unroll
      for (int j = 0; j < 8; ++j) acc[i][j] = 0.f;

    for (int kc = 0; kc < 8; ++kc) {
      const int kb = kc << 5;
      __syncthreads();
      #pragma unroll
      for (int i = 0; i < 4; ++i) {
        int flat = i * 256 + tid;
        int k = flat >> 5, m4 = (flat & 31) << 2;
        float4 vv = *reinterpret_cast<const float4*>(
            z + ((size_t)(b * DTOT + kb + k) << 12) + t0 + m4);
        *reinterpret_cast<float4*>(&As[k][m4]) = vv;
      }
      #pragma unroll
      for (int i = 0; i < 4; ++i) {
        int flat = i * 256 + tid;
        int j = flat >> 3, k4 = (flat & 7) << 2;
        float4 vv = *reinterpret_cast<const float4*>(
            cb + ((size_t)(n0 + j) << 8) + kb + k4);
        Bs[k4 + 0][j] = vv.x; Bs[k4 + 1][j] = vv.y;
        Bs[k4 + 2][j] = vv.z; Bs[k4 + 3][j] = vv.w;
      }
      __syncthreads();
      #pragma unroll 8
      for (int k = 0; k < 32; ++k) {
        float a[8], bv[8];
        *reinterpret_cast<float4*>(&a[0]) = *reinterpret_cast<const float4*>(&As[k][ty * 4]);
        *reinterpret_cast<float4*>(&a[4]) = *reinterpret_cast<const float4*>(&As[k][64 + ty * 4]);
        *reinterpret_cast<float4*>(&bv[0]) = *reinterpret_cast<const float4*>(&Bs[k][tx * 4]);
        *reinterpret_cast<float4*>(&bv[4]) = *reinterpret_cast<const float4*>(&Bs[k][64 + tx * 4]);
        #pragma unroll
        for (int i = 0; i < 8; ++i)
          #pragma unroll
          for (int j = 0; j < 8; ++j) acc[i][j] = fmaf(a[i], bv[j], acc[i][j]);
      }
    }
    float cs[8];
    #pragma unroll
    for (int j = 0; j < 8; ++j) cs[j] = csq[n0 + jcol[j]];
    #pragma unroll
    for (int i = 0; i < 8; ++i) {
      #pragma unroll
      for (int j = 0; j < 8; ++j) {
        float d = (an[i] - 2.f * acc[i][j]) + cs[j];
        int jg = n0 + jcol[j];
        if (d < rmin[i] || (d == rmin[i] && jg < ridx[i])) { rmin[i] = d; ridx[i] = jg; }
      }
    }
  }
  __syncthreads();
  float* redf = &As[0][0];
  int* redi = reinterpret_cast<int*>(&Bs[0][0]);
  #pragma unroll
  for (int i = 0; i < 8; ++i) {
    redf[mrow[i] * 16 + tx] = rmin[i];
    redi[mrow[i] * 16 + tx] = ridx[i];
  }
  __syncthreads();
  if (tid < 128) {
    int row = tid;
    float bestv = redf[row * 16]; int bi = redi[row * 16];
    #pragma unroll
    for (int x = 1; x < 16; ++x) {
      float m = redf[row * 16 + x]; int ii = redi[row * 16 + x];
      if (m < bestv || (m == bestv && ii < bi)) { bestv = m; bi = ii; }
    }
    pmin[(size_t)(r0 + row) * 4 + s] = bestv;
    pidx[(size_t)(r0 + row) * 4 + s] = bi;
  }
}

__global__ __launch_bounds__(256) void k_comb(const float* __restrict__ pmin,
                                              const int* __restrict__ pidx,
                                              int* __restrict__ widx,
                                              float* __restrict__ out1) {
  int r = blockIdx.x * 256 + threadIdx.x;
  float best = pmin[r * 4]; int bi = pidx[r * 4];
  #pragma unroll
  for (int s2 = 1; s2 < 4; ++s2) {
    float m = pmin[r * 4 + s2]; int ii = pidx[r * 4 + s2];
    if (m < best || (m == best && ii < bi)) { best = m; bi = ii; }
  }
  widx[r] = bi;
  out1[r] = (float)bi;
}

// ---------------- launch ----------------

extern "C" void kernel_launch(void* const* d_in, const int* in_sizes, int n_in,
                              void* d_out, int out_size, void* d_ws, size_t ws_size,
                              hipStream_t stream) {
  const float* z  = (const float*)d_in[0];
  const float* cb = (const float*)d_in[1];
  float* out = (float*)d_out;

  if (ws_size >= 54821000) {
    // MFMA path
    char* wsb = (char*)d_ws;
    unsigned short* Abf = (unsigned short*)wsb;                 // 16,777,216 B
    unsigned short* Bbf = (unsigned short*)(wsb + 16777216);    //  4,194,304 B
    float*  tmin = (float*)(wsb + 20971520);                    // 33,554,432 B
    float*  rn   = (float*)(wsb + 54525952);
    float*  csq  = (float*)(wsb + 54657024);
    int*    widx = (int*)(wsb + 54689792);
    double* loss = (double*)(wsb + 54820864);

    k_csq<<<NCB / 4, 256, 0, stream>>>(cb, csq, loss);
    k_rn<<<NROWS / 256, 256, 0, stream>>>(z, rn);
    k_fsq<<<(BB * DAC * TT) / 256, 256, 0, stream>>>(z, out);
    k_prepA<<<2048, 256, 0, stream>>>(z, Abf);
    k_prepB<<<8192, 256, 0, stream>>>(cb, Bbf);
    k_gemm<<<16384, 256, 0, stream>>>(Abf, Bbf, csq, tmin);
    k_rescan<<<NROWS / 64, 256, 0, stream>>>(z, cb, csq, rn, tmin, widx, out + O1);
    k_loss<<<2048, 256, 0, stream>>>(z, cb, widx, out + O0, loss);
    k_fin<<<1, 1, 0, stream>>>(loss, out + O3);
  } else {
    // round-1 fallback
    float* wsf = (float*)d_ws;
    float* csq  = wsf;
    float* rn   = wsf + 8192;
    float* pmin = wsf + 40960;
    int*   pidx = (int*)(wsf + 172032);
    int*   widx = (int*)(wsf + 303104);
    double* loss = (double*)(wsf + 335872);

    k_csq<<<NCB / 4, 256, 0, stream>>>(cb, csq, loss);
    k_rn<<<NROWS / 256, 256, 0, stream>>>(z, rn);
    k_fsq<<<(BB * DAC * TT) / 256, 256, 0, stream>>>(z, out);
    k_vq<<<(NROWS / 128) * 4, 256, 0, stream>>>(z, cb, csq, rn, pmin, pidx);
    k_comb<<<NROWS / 256, 256, 0, stream>>>(pmin, pidx, widx, out + O1);
    k_loss<<<2048, 256, 0, stream>>>(z, cb, widx, out + O0, loss);
    k_fin<<<1, 1, 0, stream>>>(loss, out + O3);
  }
}

// Round 4
// 543.186 us; speedup vs baseline: 1.9346x; 1.9346x over previous
//
#include <hip/hip_runtime.h>
#include <math.h>

#define BB 8
#define DSEM 256
#define DAC 36
#define DTOT 292
#define TT 4096
#define NCB 8192
#define NROWS (BB*TT)          // 32768

// output flat offsets (all float32)
static constexpr size_t O0 = 0;          // z_q (8,292,4096)
static constexpr size_t O1 = 9568256;    // sem_indices (8,4096)
static constexpr size_t O2 = 9601024;    // ac_codes (8,36,4096)
static constexpr size_t O3 = 10780672;   // vq_loss scalar
static constexpr size_t O4 = 10780673;   // z_ac_q (8,36,4096)

typedef _Float16 f16x8 __attribute__((ext_vector_type(8)));
typedef __attribute__((ext_vector_type(4))) float f32x4;

__device__ __forceinline__ void gload_lds16(const void* g, void* lds) {
  __builtin_amdgcn_global_load_lds(
      (const __attribute__((address_space(1))) void*)g,
      (__attribute__((address_space(3))) void*)lds, 16, 0, 0);
}

// ---------------- shared small kernels (both paths) ----------------

__global__ __launch_bounds__(256) void k_csq(const float* __restrict__ cb,
                                             float* __restrict__ csq,
                                             double* __restrict__ loss) {
  if (blockIdx.x == 0 && threadIdx.x == 0) loss[0] = 0.0;
  int w = (blockIdx.x << 2) + (threadIdx.x >> 6);
  int lane = threadIdx.x & 63;
  float4 v = *reinterpret_cast<const float4*>(cb + (size_t)w * DSEM + lane * 4);
  float s = v.x * v.x + v.y * v.y + v.z * v.z + v.w * v.w;
  for (int off = 32; off; off >>= 1) s += __shfl_xor(s, off);
  if (lane == 0) csq[w] = s;
}

__global__ __launch_bounds__(256) void k_rn(const float* __restrict__ z,
                                            float* __restrict__ rn) {
  int r = blockIdx.x * 256 + threadIdx.x;
  int b = r >> 12, t = r & 4095;
  const float* p = z + ((size_t)(b * DTOT) << 12) + t;
  double acc = 0.0;
  #pragma unroll 8
  for (int d = 0; d < DSEM; ++d) {
    float v = p[(size_t)d << 12];
    acc += (double)v * (double)v;
  }
  rn[r] = (float)acc;
}

__global__ __launch_bounds__(256) void k_fsq(const float* __restrict__ z,
                                             float* __restrict__ out) {
  int e = blockIdx.x * 256 + threadIdx.x;   // < 1179648
  int b = e / (DAC * TT);
  int rem = e - b * (DAC * TT);
  int d = rem >> 12, t = rem & 4095;
  float zv = z[((size_t)(b * DTOT + DSEM + d) << 12) + t];
  float th = (float)tanh((double)zv);
  float zb = th * 10.001f;
  float zq = rintf(zb);
  int code = (int)(zq + 10.0f);
  code = code < 0 ? 0 : (code > 20 ? 20 : code);
  out[O0 + (((size_t)(b * DTOT + DSEM + d)) << 12) + t] = zq;
  out[O2 + e] = (float)code;
  out[O4 + e] = zq;
}

__global__ __launch_bounds__(256) void k_loss(const float* __restrict__ z,
                                              const float* __restrict__ cb,
                                              const int* __restrict__ idx,
                                              float* __restrict__ out0,
                                              double* __restrict__ loss) {
  float s = 0.f;
  for (int e = blockIdx.x * 256 + threadIdx.x; e < BB * DSEM * TT; e += 2048 * 256) {
    int b = e >> 20;
    int rem = e & 1048575;
    int d = rem >> 12, t = rem & 4095;
    int r = (b << 12) + t;
    int j = idx[r];
    float c = cb[(size_t)j * DSEM + d];
    size_t zi = ((size_t)(b * DTOT + d) << 12) + t;
    float zv = z[zi];
    out0[zi] = c;
    float df = c - zv;
    s += df * df;
  }
  for (int off = 32; off; off >>= 1) s += __shfl_xor(s, off);
  __shared__ float ws4[4];
  int lane = threadIdx.x & 63, w = threadIdx.x >> 6;
  if (lane == 0) ws4[w] = s;
  __syncthreads();
  if (threadIdx.x == 0) {
    float tot = ws4[0] + ws4[1] + ws4[2] + ws4[3];
    atomicAdd(loss, (double)tot);
  }
}

__global__ void k_fin(const double* __restrict__ loss, float* __restrict__ out3) {
  out3[0] = (float)(1.25 * loss[0] / 8388608.0);
}

// ---------------- MFMA path (f16 coarse) ----------------

// transpose z_sem (b,k,t) -> A' f16 [row=(b,t)][k]
__global__ __launch_bounds__(256) void k_prepA(const float* __restrict__ z,
                                               _Float16* __restrict__ Ah) {
  __shared__ float tile[64][65];
  int bid = blockIdx.x;
  int tt = bid & 63, kt = (bid >> 6) & 3, b = bid >> 8;
  int k0 = kt * 64, t0 = tt * 64;
  int tid = threadIdx.x;
  #pragma unroll
  for (int i = 0; i < 16; ++i) {
    int flat = i * 256 + tid;
    int kk = flat >> 6, t2 = flat & 63;
    tile[kk][t2] = z[((size_t)(b * DTOT + k0 + kk) << 12) + t0 + t2];
  }
  __syncthreads();
  #pragma unroll
  for (int i = 0; i < 16; ++i) {
    int flat = i * 256 + tid;
    int t2 = flat >> 6, kk = flat & 63;
    Ah[(size_t)(b * 4096 + t0 + t2) * 256 + k0 + kk] = (_Float16)tile[kk][t2];
  }
}

// B' f16 [j][k] = f16(-32768 * cb[j][k]) = f16((-2c) * 2^14), exact scale
__global__ __launch_bounds__(256) void k_prepB(const float* __restrict__ cb,
                                               _Float16* __restrict__ Bh) {
  int e = blockIdx.x * 256 + threadIdx.x;   // < 2097152
  Bh[e] = (_Float16)(cb[e] * -32768.0f);
}

// coarse GEMM: acc = sum f16(z)*f16(-2c*2^14); per-32col-unit min of (acc*2^-14 + csq)
// tmin layout: [row][unit]  (32768 x 256 floats)
__global__ __launch_bounds__(256) void k_gemm(const _Float16* __restrict__ A,
                                              const _Float16* __restrict__ B,
                                              const float* __restrict__ csq,
                                              float* __restrict__ tmin) {
  __shared__ char smraw[128 * 68 * 4];   // 34816 B; aliases As|Bs then red
  _Float16* As = (_Float16*)smraw;           // [128][64]
  _Float16* Bs = (_Float16*)(smraw + 16384); // [128][64]
  float* red = (float*)smraw;                // [128][68]
  const float SCALE = 6.103515625e-05f;      // 2^-14, exact

  int bid = blockIdx.x;
  int wg = (bid & 7) * 2048 + (bid >> 3);   // XCD swizzle (16384 % 8 == 0)
  int mtile = wg >> 6, ntile = wg & 63;
  int rbase = mtile << 7, cbase = ntile << 7;
  int tid = threadIdx.x, lane = tid & 63, wid = tid >> 6;
  int wm = wid >> 1, wn = wid & 1;
  int l15 = lane & 15, l4 = lane >> 4;

  f32x4 acc[4][4];
  #pragma unroll
  for (int mi = 0; mi < 4; ++mi)
    #pragma unroll
    for (int ni = 0; ni < 4; ++ni) acc[mi][ni] = (f32x4){0.f, 0.f, 0.f, 0.f};

  for (int kt = 0; kt < 4; ++kt) {
    int kb = kt << 6;
    __syncthreads();
    #pragma unroll
    for (int i = 0; i < 4; ++i) {
      int flat = (wid * 4 + i) * 64 + lane;   // 0..1023
      int row = flat >> 3, kk = (flat & 7) << 3;
      gload_lds16(A + (size_t)(rbase + row) * 256 + kb + kk, (char*)As + flat * 16);
      gload_lds16(B + (size_t)(cbase + row) * 256 + kb + kk, (char*)Bs + flat * 16);
    }
    __syncthreads();
    #pragma unroll
    for (int ks = 0; ks < 2; ++ks) {
      int ko = (ks << 5) + (l4 << 3);
      f16x8 af[4], bv[4];
      #pragma unroll
      for (int mi = 0; mi < 4; ++mi)
        af[mi] = *(const f16x8*)(As + ((wm * 64 + mi * 16 + l15) << 6) + ko);
      #pragma unroll
      for (int ni = 0; ni < 4; ++ni)
        bv[ni] = *(const f16x8*)(Bs + ((wn * 64 + ni * 16 + l15) << 6) + ko);
      #pragma unroll
      for (int mi = 0; mi < 4; ++mi)
        #pragma unroll
        for (int ni = 0; ni < 4; ++ni)
          acc[mi][ni] = __builtin_amdgcn_mfma_f32_16x16x32_f16(af[mi], bv[ni], acc[mi][ni], 0, 0, 0);
    }
  }

  // epilogue: d = acc*2^-14 + csq[col]; per-row min over 32-col units
  float csv[4];
  #pragma unroll
  for (int ni = 0; ni < 4; ++ni) csv[ni] = csq[cbase + wn * 64 + ni * 16 + l15];

  __syncthreads();   // everyone done reading As/Bs before aliasing as red
  #pragma unroll
  for (int mi = 0; mi < 4; ++mi) {
    #pragma unroll
    for (int r = 0; r < 4; ++r) {
      int row = wm * 64 + mi * 16 + l4 * 4 + r;
      float v0 = fminf(fmaf(acc[mi][0][r], SCALE, csv[0]),
                       fmaf(acc[mi][1][r], SCALE, csv[1]));
      float v1 = fminf(fmaf(acc[mi][2][r], SCALE, csv[2]),
                       fmaf(acc[mi][3][r], SCALE, csv[3]));
      red[row * 68 + (wn * 2 + 0) * 16 + l15] = v0;
      red[row * 68 + (wn * 2 + 1) * 16 + l15] = v1;
    }
  }
  __syncthreads();
  if (tid < 128) {
    int row = tid;
    const float* rp = red + row * 68;
    float4 o4;
    #pragma unroll
    for (int q = 0; q < 4; ++q) {
      float m = rp[q * 16];
      #pragma unroll
      for (int x = 1; x < 16; ++x) m = fminf(m, rp[q * 16 + x]);
      ((float*)&o4)[q] = m;
    }
    *reinterpret_cast<float4*>(tmin + (size_t)(rbase + row) * 256 + ntile * 4) = o4;
  }
}

// exact scan of a pair of candidate units across 64 lanes; returns lex-min (d,j)
__device__ __forceinline__ unsigned long long scan_pair(
    const float* __restrict__ zcol, const float* __restrict__ cb,
    const float* __restrict__ csq, float an, int ua, int ub, int lane) {
  int u = (lane < 32) ? ua : ub;
  int j = (u << 5) + (lane & 31);
  const float4* cp = reinterpret_cast<const float4*>(cb + ((size_t)j << 8));
  float cq = csq[j];
  float m = 0.f;
  #pragma unroll 8
  for (int k4 = 0; k4 < 64; ++k4) {
    float4 cv = cp[k4];
    m = fmaf(zcol[(k4 * 4 + 0) * 32], cv.x, m);
    m = fmaf(zcol[(k4 * 4 + 1) * 32], cv.y, m);
    m = fmaf(zcol[(k4 * 4 + 2) * 32], cv.z, m);
    m = fmaf(zcol[(k4 * 4 + 3) * 32], cv.w, m);
  }
  float d = (an - 2.f * m) + cq;
  unsigned long long pk =
      (((unsigned long long)__float_as_uint(d)) << 32) | (unsigned int)j;
  #pragma unroll
  for (int off = 32; off; off >>= 1) {
    unsigned long long o = __shfl_xor(pk, off);
    if (o < pk) pk = o;
  }
  return pk;
}

// exact rescan: block = 32 consecutive rows; z staged coalesced (float4);
// tmin read coalesced [row][unit]; ballot walk pairs candidate units.
__global__ __launch_bounds__(256) void k_rescan(const float* __restrict__ z,
                                                const float* __restrict__ cb,
                                                const float* __restrict__ csq,
                                                const float* __restrict__ rn,
                                                const float* __restrict__ tmin,
                                                int* __restrict__ widx,
                                                float* __restrict__ out1) {
  __shared__ float zs[256][32];   // 32 KB: zs[k][t2]
  int tid = threadIdx.x;
  int row0 = blockIdx.x << 5;
  int b = row0 >> 12, t0 = row0 & 4095;
  #pragma unroll
  for (int i = 0; i < 8; ++i) {
    int flat = i * 256 + tid;          // < 2048
    int k = flat >> 3, tl4 = (flat & 7) << 2;
    float4 v = *reinterpret_cast<const float4*>(
        z + ((size_t)(b * DTOT + k) << 12) + t0 + tl4);
    *reinterpret_cast<float4*>(&zs[k][tl4]) = v;
  }
  __syncthreads();

  int wv = tid >> 6, lane = tid & 63;
  for (int rr = wv; rr < 32; rr += 4) {
    int row = row0 + rr;
    const float* tp = tmin + (size_t)row * 256;
    float v0 = tp[lane], v1 = tp[64 + lane], v2 = tp[128 + lane], v3 = tp[192 + lane];
    float g = fminf(fminf(v0, v1), fminf(v2, v3));
    #pragma unroll
    for (int off = 32; off; off >>= 1) g = fminf(g, __shfl_xor(g, off));
    float thr = g + 2e-4f;
    float an = rn[row];
    const float* zcol = &zs[0][rr];

    unsigned long long best = 0xFFFFFFFFFFFFFFFFULL;
    int ua = -1;
    for (int i = 0; i < 4; ++i) {
      float vv = (i == 0) ? v0 : (i == 1) ? v1 : (i == 2) ? v2 : v3;
      unsigned long long mask = __ballot(vv <= thr);
      while (mask) {
        int sl = __builtin_ctzll(mask);
        mask &= mask - 1;
        int u = (i << 6) + sl;
        if (ua < 0) { ua = u; continue; }
        unsigned long long pk = scan_pair(zcol, cb, csq, an, ua, u, lane);
        if (pk < best) best = pk;
        ua = -1;
      }
    }
    if (ua >= 0) {
      unsigned long long pk = scan_pair(zcol, cb, csq, an, ua, ua, lane);
      if (pk < best) best = pk;
    }
    if (lane == 0) {
      int j = (int)(best & 0xFFFFFFFFULL);
      widx[row] = j;
      out1[row] = (float)j;
    }
  }
}

// ---------------- round-1 fallback path (fp32 vector GEMM) ----------------

__global__ __launch_bounds__(256) void k_vq(const float* __restrict__ z,
                                            const float* __restrict__ cb,
                                            const float* __restrict__ csq,
                                            const float* __restrict__ rn,
                                            float* __restrict__ pmin,
                                            int* __restrict__ pidx) {
  __shared__ float As[32][132];
  __shared__ float Bs[32][132];
  const int tid = threadIdx.x;
  const int tx = tid & 15, ty = tid >> 4;
  const int mb = blockIdx.x >> 2, s = blockIdx.x & 3;
  const int r0 = mb << 7;
  const int b = r0 >> 12, t0 = r0 & 4095;
  const int nbase = s * 2048;

  int mrow[8], jcol[8];
  #pragma unroll
  for (int i = 0; i < 4; ++i) {
    mrow[i] = ty * 4 + i;  mrow[i + 4] = 64 + ty * 4 + i;
    jcol[i] = tx * 4 + i;  jcol[i + 4] = 64 + tx * 4 + i;
  }
  float an[8];
  #pragma unroll
  for (int i = 0; i < 8; ++i) an[i] = rn[r0 + mrow[i]];

  float rmin[8]; int ridx[8];
  #pragma unroll
  for (int i = 0; i < 8; ++i) { rmin[i] = 3.402823466e38f; ridx[i] = 0; }

  for (int nc = 0; nc < 16; ++nc) {
    const int n0 = nbase + nc * 128;
    float acc[8][8];
    #pragma unroll
    for (int i = 0; i < 8; ++i)
      #pragma unroll
      for (int j = 0; j < 8; ++j) acc[i][j] = 0.f;

    for (int kc = 0; kc < 8; ++kc) {
      const int kb = kc << 5;
      __syncthreads();
      #pragma unroll
      for (int i = 0; i < 4; ++i) {
        int flat = i * 256 + tid;
        int k = flat >> 5, m4 = (flat & 31) << 2;
        float4 vv = *reinterpret_cast<const float4*>(
            z + ((size_t)(b * DTOT + kb + k) << 12) + t0 + m4);
        *reinterpret_cast<float4*>(&As[k][m4]) = vv;
      }
      #pragma unroll
      for (int i = 0; i < 4; ++i) {
        int flat = i * 256 + tid;
        int j = flat >> 3, k4 = (flat & 7) << 2;
        float4 vv = *reinterpret_cast<const float4*>(
            cb + ((size_t)(n0 + j) << 8) + kb + k4);
        Bs[k4 + 0][j] = vv.x; Bs[k4 + 1][j] = vv.y;
        Bs[k4 + 2][j] = vv.z; Bs[k4 + 3][j] = vv.w;
      }
      __syncthreads();
      #pragma unroll 8
      for (int k = 0; k < 32; ++k) {
        float a[8], bv[8];
        *reinterpret_cast<float4*>(&a[0]) = *reinterpret_cast<const float4*>(&As[k][ty * 4]);
        *reinterpret_cast<float4*>(&a[4]) = *reinterpret_cast<const float4*>(&As[k][64 + ty * 4]);
        *reinterpret_cast<float4*>(&bv[0]) = *reinterpret_cast<const float4*>(&Bs[k][tx * 4]);
        *reinterpret_cast<float4*>(&bv[4]) = *reinterpret_cast<const float4*>(&Bs[k][64 + tx * 4]);
        #pragma unroll
        for (int i = 0; i < 8; ++i)
          #pragma unroll
          for (int j = 0; j < 8; ++j) acc[i][j] = fmaf(a[i], bv[j], acc[i][j]);
      }
    }
    float cs[8];
    #pragma unroll
    for (int j = 0; j < 8; ++j) cs[j] = csq[n0 + jcol[j]];
    #pragma unroll
    for (int i = 0; i < 8; ++i) {
      #pragma unroll
      for (int j = 0; j < 8; ++j) {
        float d = (an[i] - 2.f * acc[i][j]) + cs[j];
        int jg = n0 + jcol[j];
        if (d < rmin[i] || (d == rmin[i] && jg < ridx[i])) { rmin[i] = d; ridx[i] = jg; }
      }
    }
  }
  __syncthreads();
  float* redf = &As[0][0];
  int* redi = reinterpret_cast<int*>(&Bs[0][0]);
  #pragma unroll
  for (int i = 0; i < 8; ++i) {
    redf[mrow[i] * 16 + tx] = rmin[i];
    redi[mrow[i] * 16 + tx] = ridx[i];
  }
  __syncthreads();
  if (tid < 128) {
    int row = tid;
    float bestv = redf[row * 16]; int bi = redi[row * 16];
    #pragma unroll
    for (int x = 1; x < 16; ++x) {
      float m = redf[row * 16 + x]; int ii = redi[row * 16 + x];
      if (m < bestv || (m == bestv && ii < bi)) { bestv = m; bi = ii; }
    }
    pmin[(size_t)(r0 + row) * 4 + s] = bestv;
    pidx[(size_t)(r0 + row) * 4 + s] = bi;
  }
}

__global__ __launch_bounds__(256) void k_comb(const float* __restrict__ pmin,
                                              const int* __restrict__ pidx,
                                              int* __restrict__ widx,
                                              float* __restrict__ out1) {
  int r = blockIdx.x * 256 + threadIdx.x;
  float best = pmin[r * 4]; int bi = pidx[r * 4];
  #pragma unroll
  for (int s2 = 1; s2 < 4; ++s2) {
    float m = pmin[r * 4 + s2]; int ii = pidx[r * 4 + s2];
    if (m < best || (m == best && ii < bi)) { best = m; bi = ii; }
  }
  widx[r] = bi;
  out1[r] = (float)bi;
}

// ---------------- launch ----------------

extern "C" void kernel_launch(void* const* d_in, const int* in_sizes, int n_in,
                              void* d_out, int out_size, void* d_ws, size_t ws_size,
                              hipStream_t stream) {
  const float* z  = (const float*)d_in[0];
  const float* cb = (const float*)d_in[1];
  float* out = (float*)d_out;

  if (ws_size >= 54821000) {
    // MFMA path
    char* wsb = (char*)d_ws;
    _Float16* Ah = (_Float16*)wsb;                              // 16,777,216 B
    _Float16* Bh = (_Float16*)(wsb + 16777216);                 //  4,194,304 B
    float*  tmin = (float*)(wsb + 20971520);                    // 33,554,432 B
    float*  rn   = (float*)(wsb + 54525952);
    float*  csq  = (float*)(wsb + 54657024);
    int*    widx = (int*)(wsb + 54689792);
    double* loss = (double*)(wsb + 54820864);

    k_csq<<<NCB / 4, 256, 0, stream>>>(cb, csq, loss);
    k_rn<<<NROWS / 256, 256, 0, stream>>>(z, rn);
    k_fsq<<<(BB * DAC * TT) / 256, 256, 0, stream>>>(z, out);
    k_prepA<<<2048, 256, 0, stream>>>(z, Ah);
    k_prepB<<<8192, 256, 0, stream>>>(cb, Bh);
    k_gemm<<<16384, 256, 0, stream>>>(Ah, Bh, csq, tmin);
    k_rescan<<<NROWS / 32, 256, 0, stream>>>(z, cb, csq, rn, tmin, widx, out + O1);
    k_loss<<<2048, 256, 0, stream>>>(z, cb, widx, out + O0, loss);
    k_fin<<<1, 1, 0, stream>>>(loss, out + O3);
  } else {
    // round-1 fallback
    float* wsf = (float*)d_ws;
    float* csq  = wsf;
    float* rn   = wsf + 8192;
    float* pmin = wsf + 40960;
    int*   pidx = (int*)(wsf + 172032);
    int*   widx = (int*)(wsf + 303104);
    double* loss = (double*)(wsf + 335872);

    k_csq<<<NCB / 4, 256, 0, stream>>>(cb, csq, loss);
    k_rn<<<NROWS / 256, 256, 0, stream>>>(z, rn);
    k_fsq<<<(BB * DAC * TT) / 256, 256, 0, stream>>>(z, out);
    k_vq<<<(NROWS / 128) * 4, 256, 0, stream>>>(z, cb, csq, rn, pmin, pidx);
    k_comb<<<NROWS / 256, 256, 0, stream>>>(pmin, pidx, widx, out + O1);
    k_loss<<<2048, 256, 0, stream>>>(z, cb, widx, out + O0, loss);
    k_fin<<<1, 1, 0, stream>>>(loss, out + O3);
  }
}